// Round 4
// baseline (277.077 us; speedup 1.0000x reference)
//
#include <hip/hip_runtime.h>

#define B_    4
#define DEC_  256
#define ENC_  1024
#define D_    1024
#define A_    144
#define V_    50257
#define NROW_ (B_ * DEC_)

typedef __attribute__((ext_vector_type(4))) float float4v;

// ---------------- kernel 1: p_gen = sigmoid(hidden . W_pgen + b) -> out tail (fp32) ----------------
// grid = NROW_ rows, block = 256 (each thread: 4 floats of D=1024)
__global__ void k_pgen(const float* __restrict__ hid, const float* __restrict__ Wp,
                       const float* __restrict__ bp, float* __restrict__ tail){
  int row = blockIdx.x, t = threadIdx.x;
  float4v hv = reinterpret_cast<const float4v*>(hid + (size_t)row * D_)[t];
  float4v wv = reinterpret_cast<const float4v*>(Wp)[t];
  float s = hv[0]*wv[0] + hv[1]*wv[1] + hv[2]*wv[2] + hv[3]*wv[3];
  for (int o = 32; o > 0; o >>= 1) s += __shfl_down(s, o, 64);
  __shared__ float red[4];
  if ((t & 63) == 0) red[t >> 6] = s;
  __syncthreads();
  if (t == 0){
    float tot = red[0] + red[1] + red[2] + red[3] + bp[0];
    tail[row] = 1.f / (1.f + __expf(-tot));
  }
}

// ---------------- kernel 2: out = p_gen * ovp (fp32, 4-wide) ----------------
__global__ void k_base(const float* __restrict__ ovp, const float* __restrict__ tail,
                       float* __restrict__ out){
  const unsigned N4 = (unsigned)(((size_t)NROW_ * V_) / 4);   // 51,463,168 / 4 exact
  unsigned stride = gridDim.x * blockDim.x;
  for (unsigned vi = blockIdx.x * blockDim.x + threadIdx.x; vi < N4; vi += stride){
    unsigned i0 = vi * 4u;
    unsigned r0 = i0 / (unsigned)V_;
    unsigned r1 = (i0 + 3u) / (unsigned)V_;
    float4v a = reinterpret_cast<const float4v*>(ovp)[vi];
    float4v o;
    float pg0 = tail[r0];
    if (r0 == r1){
#pragma unroll
      for (int k = 0; k < 4; ++k) o[k] = pg0 * a[k];
    } else {
      float pg1 = tail[r1];
      unsigned bnd = r1 * (unsigned)V_;
#pragma unroll
      for (int k = 0; k < 4; ++k)
        o[k] = (((i0 + (unsigned)k) < bnd) ? pg0 : pg1) * a[k];
    }
    reinterpret_cast<float4v*>(out)[vi] = o;
  }
}

// ---------------- kernel 3: copy logits + dedup scatter, one block per (b,dec) row ----------------
// val_e = (1-pg)*relu(att[row,e,:].W_add + b_add); LDS hash sums duplicate token ids;
// CAS-winning leader writes out[row*V+id] = pg*ovp[oi] + sum (overwrites k_base's value).
__global__ __launch_bounds__(256) void k_valscat(const int* __restrict__ ids,
                                                 const float* __restrict__ att,
                                                 const float* __restrict__ ovp,
                                                 const float* __restrict__ Wa,
                                                 const float* __restrict__ ba,
                                                 const float* __restrict__ tail,
                                                 float* __restrict__ out){
  __shared__ float sW[A_];
  __shared__ int   sid[ENC_];
  __shared__ int   hkey[2048];
  __shared__ float hval[2048];

  int row = blockIdx.x, t = threadIdx.x;
  int b = row >> 8;                       // row = b*DEC + dec
  float pg = tail[row];

  if (t < A_) sW[t] = Wa[t];
  for (int i = t; i < 2048; i += 256){ hkey[i] = -1; hval[i] = 0.f; }
  for (int i = t; i < ENC_; i += 256) sid[i] = ids[b * ENC_ + i];
  __syncthreads();

  float bav = ba[0];
  float one_m = 1.f - pg;

  unsigned slotk[4];
  int      leadk[4];

#pragma unroll
  for (int k = 0; k < 4; ++k){
    int e = k * 256 + t;
    const float4v* ap = reinterpret_cast<const float4v*>(att + ((size_t)row * ENC_ + e) * A_);
    float acc = 0.f;
#pragma unroll
    for (int j = 0; j < A_ / 4; ++j){
      float4v v = ap[j];
      acc += v[0]*sW[j*4+0] + v[1]*sW[j*4+1] + v[2]*sW[j*4+2] + v[3]*sW[j*4+3];
    }
    float x = acc + bav;
    x = x > 0.f ? x : 0.f;
    float val = one_m * x;

    int id = sid[e];
    unsigned h = (((unsigned)id * 2654435761u) >> 16) & 2047u;
    int lead = 0;
    while (true){
      int prev = atomicCAS(&hkey[h], -1, id);
      if (prev == -1){ lead = 1; break; }
      if (prev == id) break;
      h = (h + 1) & 2047u;
    }
    atomicAdd(&hval[h], val);
    slotk[k] = h;
    leadk[k] = lead;
  }
  __syncthreads();

#pragma unroll
  for (int k = 0; k < 4; ++k){
    if (leadk[k]){
      int e = k * 256 + t;
      int id = sid[e];
      size_t oi = (size_t)row * V_ + id;
      out[oi] = pg * ovp[oi] + hval[slotk[k]];
    }
  }
}

extern "C" void kernel_launch(void* const* d_in, const int* in_sizes, int n_in,
                              void* d_out, int out_size, void* d_ws, size_t ws_size,
                              hipStream_t stream) {
  (void)in_sizes; (void)n_in; (void)d_ws; (void)ws_size; (void)out_size;
  const int*   ids = (const int*)  d_in[0];
  const float* att = (const float*)d_in[1];
  const float* hid = (const float*)d_in[2];
  const float* ovp = (const float*)d_in[3];
  const float* Wp  = (const float*)d_in[4];
  const float* bp  = (const float*)d_in[5];
  const float* Wa  = (const float*)d_in[6];
  const float* ba  = (const float*)d_in[7];
  float* out  = (float*)d_out;
  float* tail = out + (size_t)NROW_ * V_;   // p_gen output (fp32)

  k_pgen   <<<NROW_, 256, 0, stream>>>(hid, Wp, bp, tail);
  k_base   <<<4096,  256, 0, stream>>>(ovp, tail, out);
  k_valscat<<<NROW_, 256, 0, stream>>>(ids, att, ovp, Wa, ba, tail, out);
}